// Round 1
// baseline (334.512 us; speedup 1.0000x reference)
//
#include <hip/hip_runtime.h>
#include <math.h>

// Problem constants (from reference): B=64, N=8191, D=128, P=33, K=16,
// MARGIN=1, TAU=1, THRESH=100. Only batch 63 affects the loss; err_pos and
// sparsity are constants. detect_smooth is always "smooth" (gap bound ~1.3
// << 16*ln(100)=73.7), so only f_sk (log elementary symmetric poly e_16 of
// exp(v)) is needed.
#define NN 8191
#define DD 128
#define PP 33

// ---------------------------------------------------------------------------
// Kernel 1: x1[p][n'] = raw/(anorm[p]*gss[j]) + (n'>=32 ? 1 : 0), batch 63,
// diagonal j==p removed (n' = j - (j>p)). 128 blocks x 64 columns.
// ---------------------------------------------------------------------------
__global__ __launch_bounds__(256) void k_score(const float* __restrict__ x,
                                               float* __restrict__ x1)
{
    __shared__ float Xt[64][132];     // 64 columns x 128 d (pad 132)
    __shared__ float At[PP][132];     // 33 anchors x 128 d
    __shared__ float accS[4][PP][64]; // partial dots per d-slice
    __shared__ float gssS[4][64];
    __shared__ float inv_an[PP];

    const float* base = x + (size_t)63 * 8192 * DD;  // Xg[63]
    const int b = blockIdx.x;
    const int tid = threadIdx.x;

    // stage X tile (64 rows x 128 floats) coalesced float4
    {
        const float4* g = (const float4*)(base + (size_t)b * 64 * DD);
        #pragma unroll
        for (int k = 0; k < 8; ++k) {
            int i = tid + k * 256;
            int row = i >> 5, c4 = i & 31;
            float4 v = g[row * 32 + c4];
            float* d = &Xt[row][c4 * 4];
            d[0] = v.x; d[1] = v.y; d[2] = v.z; d[3] = v.w;
        }
    }
    // stage A (rows 0..32 of Xg[63])
    {
        const float4* g = (const float4*)base;
        #pragma unroll
        for (int k = 0; k < 5; ++k) {
            int i = tid + k * 256;
            if (i < PP * 32) {
                int row = i >> 5, c4 = i & 31;
                float4 v = g[row * 32 + c4];
                float* d = &At[row][c4 * 4];
                d[0] = v.x; d[1] = v.y; d[2] = v.z; d[3] = v.w;
            }
        }
    }
    __syncthreads();

    if (tid < PP) {
        float ss = 0.f;
        for (int d = 0; d < DD; ++d) { float a = At[tid][d]; ss += a * a; }
        inv_an[tid] = 1.0f / sqrtf(ss);
    }

    // compute phase: thread = (d-slice s of 32, column c)
    const int s = tid >> 6, c = tid & 63;
    float xr[32];
    {
        const float* xrow = &Xt[c][s * 32];
        #pragma unroll
        for (int d = 0; d < 32; ++d) xr[d] = xrow[d];
    }
    float gp = 0.f;
    #pragma unroll
    for (int d = 0; d < 32; ++d) gp += xr[d] * xr[d];
    gssS[s][c] = gp;

    for (int p = 0; p < PP; ++p) {
        const float4* ap = (const float4*)&At[p][s * 32];  // wave-uniform -> broadcast
        float a0 = 0.f;
        #pragma unroll
        for (int i = 0; i < 8; ++i) {
            float4 a = ap[i];
            a0 += a.x * xr[4*i] + a.y * xr[4*i+1] + a.z * xr[4*i+2] + a.w * xr[4*i+3];
        }
        accS[s][p][c] = a0;
    }
    __syncthreads();

    // output phase: reduce 4 slices, apply norm + margin, scatter (diag removed)
    for (int idx = tid; idx < PP * 64; idx += 256) {
        int p = idx >> 6, cc = idx & 63;
        float raw = accS[0][p][cc] + accS[1][p][cc] + accS[2][p][cc] + accS[3][p][cc];
        float g   = gssS[0][cc] + gssS[1][cc] + gssS[2][cc] + gssS[3][cc];
        int j = b * 64 + cc;
        if (j == p) continue;
        int np = j - (j > p ? 1 : 0);
        float val = raw * inv_an[p] / g + ((np >= 32) ? 1.0f : 0.0f);
        x1[(size_t)p * 8192 + np] = val;
    }
}

// ---------------------------------------------------------------------------
// Kernel 2: per row r, v1[r] = log e_16(exp(x1[r][0..8190])).
// 256 threads: strided 32-element leaf DPs (f64 linear space — no overflow,
// e_16(full) ~ e^120 << f64 max) then 8 levels of 17-coeff poly convolution.
// ---------------------------------------------------------------------------
__global__ __launch_bounds__(256) void k_dp(const float* __restrict__ x1,
                                            float* __restrict__ v1)
{
    __shared__ double bufA[256][17];
    __shared__ double bufB[128][17];
    const int r = blockIdx.x, tid = threadIdx.x;
    const float* row = x1 + (size_t)r * 8192;

    double c[17];
    c[0] = 1.0;
    #pragma unroll
    for (int j = 1; j <= 16; ++j) c[j] = 0.0;

    for (int i = 0; i < 32; ++i) {
        int idx = i * 256 + tid;          // strided -> coalesced loads
        if (idx < NN) {
            double w = (double)expf(row[idx]);
            #pragma unroll
            for (int j = 16; j >= 1; --j) c[j] = fma(c[j-1], w, c[j]);
        }
    }
    #pragma unroll
    for (int j = 0; j <= 16; ++j) bufA[tid][j] = c[j];
    __syncthreads();

    double (*src)[17] = bufA;
    double (*dst)[17] = bufB;
    for (int M = 128; M >= 1; M >>= 1) {
        for (int idx = tid; idx < M * 17; idx += 256) {
            int cc = idx / 17;
            int j  = idx - cc * 17;
            const double* p1 = src[2 * cc];
            const double* p2 = src[2 * cc + 1];
            double sacc = 0.0;
            for (int a = 0; a <= j; ++a) sacc = fma(p1[a], p2[j - a], sacc);
            dst[cc][j] = sacc;
        }
        __syncthreads();
        double (*t)[17] = src; src = dst; dst = t;
    }
    if (tid == 0) v1[r] = (float)log(src[0][16]);
}

// ---------------------------------------------------------------------------
// Kernel 3: v2[r] over first 32 cols (x2), reduce (v1-v2), write outputs.
// ---------------------------------------------------------------------------
__global__ __launch_bounds__(64) void k_final(const float* __restrict__ x1,
                                              const float* __restrict__ v1,
                                              float* __restrict__ out)
{
    const int tid = threadIdx.x;
    float val = 0.f;
    if (tid < PP) {
        const float* row = x1 + (size_t)tid * 8192;
        double c[17];
        c[0] = 1.0;
        #pragma unroll
        for (int j = 1; j <= 16; ++j) c[j] = 0.0;
        for (int i = 0; i < 32; ++i) {
            double w = (double)expf(row[i]);
            #pragma unroll
            for (int j = 16; j >= 1; --j) c[j] = fma(c[j-1], w, c[j]);
        }
        float v2 = (float)log(c[16]);
        val = v1[tid] - v2;
    }
    #pragma unroll
    for (int off = 32; off > 0; off >>= 1) val += __shfl_down(val, off);
    if (tid == 0) {
        out[0] = val / (float)PP;                 // loss
        out[1] = 0.0f;                            // sparsity (constant)
        out[2] = 2.0f * 33792.0f / 17299392.0f;   // err_pos (constant)
    }
}

extern "C" void kernel_launch(void* const* d_in, const int* in_sizes, int n_in,
                              void* d_out, int out_size, void* d_ws, size_t ws_size,
                              hipStream_t stream)
{
    const float* x = (const float*)d_in[0];
    float* ws_x1 = (float*)d_ws;                       // 33 rows, stride 8192
    float* ws_v1 = (float*)d_ws + (size_t)PP * 8192;   // 33 floats

    k_score<<<128, 256, 0, stream>>>(x, ws_x1);
    k_dp<<<PP, 256, 0, stream>>>(ws_x1, ws_v1);
    k_final<<<1, 64, 0, stream>>>(ws_x1, ws_v1, (float*)d_out);
}